// Round 1
// baseline (84.777 us; speedup 1.0000x reference)
//
#include <hip/hip_runtime.h>

// QuantumNAT: 4-qubit, 3-layer circuit. Key reduction:
//   <Z_q> = Tr[ (W^dag Z_q W) * (rho_0 x rho_1 x rho_2 x rho_3) ]
// with rho_i = (I - sin(x_i) Y + cos(x_i) Z)/2  (RX(x)|0> has no X component).
// => <Z_q> = sum over 81 Pauli strings {I,Y,Z}^4 of coef_q[P] * prod_i m_i(P_i)
// with m(I)=1, m(Y)=-sin(x_i), m(Z)=cos(x_i). coef depends only on weights:
// precomputed by a tiny 1-block prep kernel into d_ws.

#define NQ 4
#define NLAYERS 3
#define DIM 16
#define NPAULI 81
#define SPT 4
#define BLOCK 256

__device__ __forceinline__ float2 cmul(float2 a, float2 b) {
    return make_float2(a.x * b.x - a.y * b.y, a.x * b.y + a.y * b.x);
}
__device__ __forceinline__ float2 cadd(float2 a, float2 b) {
    return make_float2(a.x + b.x, a.y + b.y);
}

// ---------------- prep: build W (16x16), A_q = W^dag Z_q W, Pauli coefs ----
__global__ __launch_bounds__(256) void qnat_prep(const float* __restrict__ w,
                                                 float* __restrict__ coef) {
    __shared__ float2 W[DIM][DIM];       // W[row][col]
    __shared__ float2 A[NQ][DIM][DIM];   // A_q
    __shared__ float2 U[NLAYERS * NQ][4];
    const int tid = threadIdx.x;

    // 1) all 12 fused single-qubit gates U = RZ(w2) @ RY(w1) @ RX(w0)
    if (tid < NLAYERS * NQ) {
        float th0 = w[tid * 3 + 0], th1 = w[tid * 3 + 1], th2 = w[tid * 3 + 2];
        float sx, cx; __sincosf(0.5f * th0, &sx, &cx);
        float sy, cy; __sincosf(0.5f * th1, &sy, &cy);
        float sz, cz; __sincosf(0.5f * th2, &sz, &cz);
        float2 RXm[2][2], RYm[2][2], RZm[2][2], M[2][2];
        RXm[0][0] = make_float2(cx, 0.f);  RXm[0][1] = make_float2(0.f, -sx);
        RXm[1][0] = make_float2(0.f, -sx); RXm[1][1] = make_float2(cx, 0.f);
        RYm[0][0] = make_float2(cy, 0.f);  RYm[0][1] = make_float2(-sy, 0.f);
        RYm[1][0] = make_float2(sy, 0.f);  RYm[1][1] = make_float2(cy, 0.f);
        RZm[0][0] = make_float2(cz, -sz);  RZm[0][1] = make_float2(0.f, 0.f);
        RZm[1][0] = make_float2(0.f, 0.f); RZm[1][1] = make_float2(cz, sz);
        for (int i = 0; i < 2; ++i)
            for (int j = 0; j < 2; ++j)
                M[i][j] = cadd(cmul(RYm[i][0], RXm[0][j]), cmul(RYm[i][1], RXm[1][j]));
        for (int i = 0; i < 2; ++i)
            for (int j = 0; j < 2; ++j)
                U[tid][i * 2 + j] = cadd(cmul(RZm[i][0], M[0][j]), cmul(RZm[i][1], M[1][j]));
    }
    // 2) W = I
    {
        int r = tid >> 4, c = tid & 15;
        W[r][c] = make_float2(r == c ? 1.f : 0.f, 0.f);
    }
    __syncthreads();

    // 3) apply gates chronologically: W <- G * W
    for (int layer = 0; layer < NLAYERS; ++layer) {
        for (int i = 0; i < NQ; ++i) {
            int g = layer * NQ + i;
            float2 g00 = U[g][0], g01 = U[g][1], g10 = U[g][2], g11 = U[g][3];
            int pos = 3 - i;  // bit position of qubit i (qubit 0 = MSB)
            float2 a, b; int r0 = 0, r1 = 0, c = 0;
            if (tid < 128) {                  // 16 cols x 8 row-pairs
                c = tid & 15;
                int p = tid >> 4;             // 0..7 index over other bits
                int low = p & ((1 << pos) - 1);
                int high = p >> pos;
                r0 = (high << (pos + 1)) | low;
                r1 = r0 | (1 << pos);
                a = W[r0][c]; b = W[r1][c];
            }
            __syncthreads();
            if (tid < 128) {
                W[r0][c] = cadd(cmul(g00, a), cmul(g01, b));
                W[r1][c] = cadd(cmul(g10, a), cmul(g11, b));
            }
            __syncthreads();
        }
        // CNOT chain (0->1),(1->2),(2->3) composed into one row permutation:
        // W'[r] = W[s01(s12(s23(r)))]
        {
            int r = tid >> 4, c = tid & 15;
            int x = r;
            if (x & 2) x ^= 1;   // s23: flip qubit3(pos0) if qubit2(pos1)
            if (x & 4) x ^= 2;   // s12
            if (x & 8) x ^= 4;   // s01
            float2 v = W[x][c];
            __syncthreads();
            W[r][c] = v;
            __syncthreads();
        }
    }

    // 4) A_q[j][k] = sum_b conj(W[b][j]) * z_q(b) * W[b][k]
    for (int task = tid; task < NQ * DIM * DIM; task += BLOCK) {
        int q = task >> 8, j = (task >> 4) & 15, k = task & 15;
        int pos = 3 - q;
        float2 acc = make_float2(0.f, 0.f);
        for (int b = 0; b < DIM; ++b) {
            float z = ((b >> pos) & 1) ? -1.f : 1.f;
            float2 wj = W[b][j], wk = W[b][k];
            acc.x += z * (wj.x * wk.x + wj.y * wk.y);
            acc.y += z * (wj.x * wk.y - wj.y * wk.x);
        }
        A[q][j][k] = acc;
    }
    __syncthreads();

    // 5) coef[q*81 + P] = Re(Tr[A_q * PauliString(P)]) / 16
    //    digit encoding per qubit: 0=I, 1=Y, 2=Z; P = ((p0*3+p1)*3+p2)*3+p3
    for (int task = tid; task < NQ * NPAULI; task += BLOCK) {
        int q = task / NPAULI, P = task % NPAULI;
        int p0 = P / 27, p1 = (P / 9) % 3, p2 = (P / 3) % 3, p3 = P % 3;
        int p[4] = { p0, p1, p2, p3 };
        int flip = 0;
        for (int i = 0; i < 4; ++i)
            if (p[i] == 1) flip |= 1 << (3 - i);
        float accr = 0.f;
        for (int j = 0; j < DIM; ++j) {
            int k = j ^ flip;
            // per-qubit factor: I -> 1 ; Z -> (1-2*j_i) ; Y -> i*(1-2*j_i)
            int ny = 0; float sgn = 1.f;
            for (int i = 0; i < 4; ++i) {
                int ji = (j >> (3 - i)) & 1;
                if (p[i] != 0 && ji) sgn = -sgn;
                if (p[i] == 1) ny++;
            }
            float phr, phi;
            switch (ny & 3) {
                case 0:  phr = sgn;  phi = 0.f;  break;
                case 1:  phr = 0.f;  phi = sgn;  break;
                case 2:  phr = -sgn; phi = 0.f;  break;
                default: phr = 0.f;  phi = -sgn; break;
            }
            float2 a = A[q][j][k];
            accr += a.x * phr - a.y * phi;   // result is real (A Hermitian)
        }
        coef[task] = accr * (1.f / 16.f);
    }
}

// ---------------- main: per-sample 81-term multilinear form --------------
__global__ __launch_bounds__(256) void qnat_main(const float4* __restrict__ x4,
                                                 const float* __restrict__ C,
                                                 float4* __restrict__ out4,
                                                 int B) {
    const int tid = threadIdx.x;
    const int base = blockIdx.x * (BLOCK * SPT) + tid;

    float t01[SPT][9], t23[SPT][9];
#pragma unroll
    for (int k = 0; k < SPT; ++k) {
        int s = base + k * BLOCK;
        float4 xv = (s < B) ? x4[s] : make_float4(0.f, 0.f, 0.f, 0.f);
        float s0, c0; __sincosf(xv.x, &s0, &c0);
        float s1, c1; __sincosf(xv.y, &s1, &c1);
        float s2, c2; __sincosf(xv.z, &s2, &c2);
        float s3, c3; __sincosf(xv.w, &s3, &c3);
        float m0[3] = { 1.f, -s0, c0 }, m1[3] = { 1.f, -s1, c1 };
        float m2[3] = { 1.f, -s2, c2 }, m3[3] = { 1.f, -s3, c3 };
#pragma unroll
        for (int a = 0; a < 3; ++a)
#pragma unroll
            for (int b = 0; b < 3; ++b) {
                t01[k][a * 3 + b] = m0[a] * m1[b];
                t23[k][a * 3 + b] = m2[a] * m3[b];
            }
    }

    float acc[SPT][4];
#pragma unroll
    for (int k = 0; k < SPT; ++k)
#pragma unroll
        for (int q = 0; q < 4; ++q) acc[k][q] = 0.f;

    // coef reads are wave-uniform constant offsets -> expect s_load broadcast
#pragma unroll
    for (int q = 0; q < 4; ++q) {
#pragma unroll
        for (int a = 0; a < 9; ++a) {
            float c[9];
#pragma unroll
            for (int b = 0; b < 9; ++b) c[b] = C[q * 81 + a * 9 + b];
#pragma unroll
            for (int k = 0; k < SPT; ++k) {
                float inner = 0.f;
#pragma unroll
                for (int b = 0; b < 9; ++b) inner = fmaf(c[b], t23[k][b], inner);
                acc[k][q] = fmaf(t01[k][a], inner, acc[k][q]);
            }
        }
    }

#pragma unroll
    for (int k = 0; k < SPT; ++k) {
        int s = base + k * BLOCK;
        if (s < B)
            out4[s] = make_float4(acc[k][0], acc[k][1], acc[k][2], acc[k][3]);
    }
}

extern "C" void kernel_launch(void* const* d_in, const int* in_sizes, int n_in,
                              void* d_out, int out_size, void* d_ws, size_t ws_size,
                              hipStream_t stream) {
    const float* x = (const float*)d_in[0];   // [B,4] fp32
    const float* w = (const float*)d_in[1];   // [3,4,3] fp32
    float* out = (float*)d_out;               // [B,4] fp32
    float* coef = (float*)d_ws;               // 4*81 floats scratch
    int B = in_sizes[0] / 4;

    qnat_prep<<<1, 256, 0, stream>>>(w, coef);
    int grid = (B + BLOCK * SPT - 1) / (BLOCK * SPT);
    qnat_main<<<grid, BLOCK, 0, stream>>>((const float4*)x, coef, (float4*)out, B);
}

// Round 2
// 83.411 us; speedup vs baseline: 1.0164x; 1.0164x over previous
//
#include <hip/hip_runtime.h>

// QuantumNAT: 4-qubit, 3-layer circuit. Reduction:
//   <Z_q> = Tr[ (W^dag Z_q W) * (rho_0 x rho_1 x rho_2 x rho_3) ]
// with rho_i = (I - sin(x_i) Y + cos(x_i) Z)/2  (RX(x)|0> has no X component).
// => <Z_q> = sum over 81 Pauli strings {I,Y,Z}^4 of coef_q[P] * prod_i m_i(P_i),
// m(I)=1, m(Y)=-sin(x_i), m(Z)=cos(x_i). coef depends only on weights.
//
// R2: single fused kernel. Every block recomputes the 324-entry coef table
// into LDS (~2us parallel prep; removes the prep dispatch + graph edge and
// all d_ws use), then evaluates the multilinear form with coefs read from
// LDS via broadcast ds_reads (same-address across lanes -> conflict-free).

#define NQ 4
#define NLAYERS 3
#define DIM 16
#define NPAULI 81
#define SPT 4
#define BLOCK 256

__device__ __forceinline__ float2 cmul(float2 a, float2 b) {
    return make_float2(a.x * b.x - a.y * b.y, a.x * b.y + a.y * b.x);
}
__device__ __forceinline__ float2 cadd(float2 a, float2 b) {
    return make_float2(a.x + b.x, a.y + b.y);
}

__global__ __launch_bounds__(256) void qnat_fused(const float4* __restrict__ x4,
                                                  const float* __restrict__ w,
                                                  float4* __restrict__ out4,
                                                  int B) {
    __shared__ float2 W[DIM][DIM];       // W[row][col]
    __shared__ float2 A[NQ][DIM][DIM];   // A_q = W^dag Z_q W
    __shared__ float2 U[NLAYERS * NQ][4];
    __shared__ float Cs[NQ * NPAULI];    // Pauli coefficients
    const int tid = threadIdx.x;

    // ---------------- prep phase (redundant per block, ~2us) ----------------
    // 1) all 12 fused single-qubit gates U = RZ(w2) @ RY(w1) @ RX(w0)
    if (tid < NLAYERS * NQ) {
        float th0 = w[tid * 3 + 0], th1 = w[tid * 3 + 1], th2 = w[tid * 3 + 2];
        float sx, cx; __sincosf(0.5f * th0, &sx, &cx);
        float sy, cy; __sincosf(0.5f * th1, &sy, &cy);
        float sz, cz; __sincosf(0.5f * th2, &sz, &cz);
        float2 RXm[2][2], RYm[2][2], RZm[2][2], M[2][2];
        RXm[0][0] = make_float2(cx, 0.f);  RXm[0][1] = make_float2(0.f, -sx);
        RXm[1][0] = make_float2(0.f, -sx); RXm[1][1] = make_float2(cx, 0.f);
        RYm[0][0] = make_float2(cy, 0.f);  RYm[0][1] = make_float2(-sy, 0.f);
        RYm[1][0] = make_float2(sy, 0.f);  RYm[1][1] = make_float2(cy, 0.f);
        RZm[0][0] = make_float2(cz, -sz);  RZm[0][1] = make_float2(0.f, 0.f);
        RZm[1][0] = make_float2(0.f, 0.f); RZm[1][1] = make_float2(cz, sz);
        for (int i = 0; i < 2; ++i)
            for (int j = 0; j < 2; ++j)
                M[i][j] = cadd(cmul(RYm[i][0], RXm[0][j]), cmul(RYm[i][1], RXm[1][j]));
        for (int i = 0; i < 2; ++i)
            for (int j = 0; j < 2; ++j)
                U[tid][i * 2 + j] = cadd(cmul(RZm[i][0], M[0][j]), cmul(RZm[i][1], M[1][j]));
    }
    // 2) W = I
    {
        int r = tid >> 4, c = tid & 15;
        W[r][c] = make_float2(r == c ? 1.f : 0.f, 0.f);
    }
    __syncthreads();

    // 3) apply gates chronologically: W <- G * W
    for (int layer = 0; layer < NLAYERS; ++layer) {
        for (int i = 0; i < NQ; ++i) {
            int g = layer * NQ + i;
            float2 g00 = U[g][0], g01 = U[g][1], g10 = U[g][2], g11 = U[g][3];
            int pos = 3 - i;  // bit position of qubit i (qubit 0 = MSB)
            float2 a, b; int r0 = 0, r1 = 0, c = 0;
            if (tid < 128) {                  // 16 cols x 8 row-pairs
                c = tid & 15;
                int p = tid >> 4;             // 0..7 index over other bits
                int low = p & ((1 << pos) - 1);
                int high = p >> pos;
                r0 = (high << (pos + 1)) | low;
                r1 = r0 | (1 << pos);
                a = W[r0][c]; b = W[r1][c];
            }
            __syncthreads();
            if (tid < 128) {
                W[r0][c] = cadd(cmul(g00, a), cmul(g01, b));
                W[r1][c] = cadd(cmul(g10, a), cmul(g11, b));
            }
            __syncthreads();
        }
        // CNOT chain (0->1),(1->2),(2->3) composed into one row permutation:
        // W'[r] = W[s01(s12(s23(r)))]
        {
            int r = tid >> 4, c = tid & 15;
            int x = r;
            if (x & 2) x ^= 1;   // s23: flip qubit3(pos0) if qubit2(pos1)
            if (x & 4) x ^= 2;   // s12
            if (x & 8) x ^= 4;   // s01
            float2 v = W[x][c];
            __syncthreads();
            W[r][c] = v;
            __syncthreads();
        }
    }

    // 4) A_q[j][k] = sum_b conj(W[b][j]) * z_q(b) * W[b][k]
    for (int task = tid; task < NQ * DIM * DIM; task += BLOCK) {
        int q = task >> 8, j = (task >> 4) & 15, k = task & 15;
        int pos = 3 - q;
        float2 acc = make_float2(0.f, 0.f);
        for (int b = 0; b < DIM; ++b) {
            float z = ((b >> pos) & 1) ? -1.f : 1.f;
            float2 wj = W[b][j], wk = W[b][k];
            acc.x += z * (wj.x * wk.x + wj.y * wk.y);
            acc.y += z * (wj.x * wk.y - wj.y * wk.x);
        }
        A[q][j][k] = acc;
    }
    __syncthreads();

    // 5) Cs[q*81 + P] = Re(Tr[A_q * PauliString(P)]) / 16
    //    digit encoding per qubit: 0=I, 1=Y, 2=Z; P = ((p0*3+p1)*3+p2)*3+p3
    for (int task = tid; task < NQ * NPAULI; task += BLOCK) {
        int q = task / NPAULI, P = task % NPAULI;
        int p0 = P / 27, p1 = (P / 9) % 3, p2 = (P / 3) % 3, p3 = P % 3;
        int p[4] = { p0, p1, p2, p3 };
        int flip = 0;
        for (int i = 0; i < 4; ++i)
            if (p[i] == 1) flip |= 1 << (3 - i);
        float accr = 0.f;
        for (int j = 0; j < DIM; ++j) {
            int k = j ^ flip;
            int ny = 0; float sgn = 1.f;
            for (int i = 0; i < 4; ++i) {
                int ji = (j >> (3 - i)) & 1;
                if (p[i] != 0 && ji) sgn = -sgn;
                if (p[i] == 1) ny++;
            }
            float phr, phi;
            switch (ny & 3) {
                case 0:  phr = sgn;  phi = 0.f;  break;
                case 1:  phr = 0.f;  phi = sgn;  break;
                case 2:  phr = -sgn; phi = 0.f;  break;
                default: phr = 0.f;  phi = -sgn; break;
            }
            float2 a = A[q][j][k];
            accr += a.x * phr - a.y * phi;   // result is real (A Hermitian)
        }
        Cs[task] = accr * (1.f / 16.f);
    }
    __syncthreads();

    // ---------------- main phase: 81-term multilinear form ----------------
    const int base = blockIdx.x * (BLOCK * SPT) + tid;

    float t01[SPT][9], t23[SPT][9];
#pragma unroll
    for (int k = 0; k < SPT; ++k) {
        int s = base + k * BLOCK;
        float4 xv = (s < B) ? x4[s] : make_float4(0.f, 0.f, 0.f, 0.f);
        float s0, c0; __sincosf(xv.x, &s0, &c0);
        float s1, c1; __sincosf(xv.y, &s1, &c1);
        float s2, c2; __sincosf(xv.z, &s2, &c2);
        float s3, c3; __sincosf(xv.w, &s3, &c3);
        float m0[3] = { 1.f, -s0, c0 }, m1[3] = { 1.f, -s1, c1 };
        float m2[3] = { 1.f, -s2, c2 }, m3[3] = { 1.f, -s3, c3 };
#pragma unroll
        for (int a = 0; a < 3; ++a)
#pragma unroll
            for (int b = 0; b < 3; ++b) {
                t01[k][a * 3 + b] = m0[a] * m1[b];
                t23[k][a * 3 + b] = m2[a] * m3[b];
            }
    }

    float acc[SPT][4];
#pragma unroll
    for (int k = 0; k < SPT; ++k)
#pragma unroll
        for (int q = 0; q < 4; ++q) acc[k][q] = 0.f;

#pragma unroll
    for (int q = 0; q < 4; ++q) {
#pragma unroll
        for (int a = 0; a < 9; ++a) {
            float c[9];
#pragma unroll
            for (int b = 0; b < 9; ++b) c[b] = Cs[q * 81 + a * 9 + b];
#pragma unroll
            for (int k = 0; k < SPT; ++k) {
                float inner = 0.f;
#pragma unroll
                for (int b = 0; b < 9; ++b) inner = fmaf(c[b], t23[k][b], inner);
                acc[k][q] = fmaf(t01[k][a], inner, acc[k][q]);
            }
        }
    }

#pragma unroll
    for (int k = 0; k < SPT; ++k) {
        int s = base + k * BLOCK;
        if (s < B)
            out4[s] = make_float4(acc[k][0], acc[k][1], acc[k][2], acc[k][3]);
    }
}

extern "C" void kernel_launch(void* const* d_in, const int* in_sizes, int n_in,
                              void* d_out, int out_size, void* d_ws, size_t ws_size,
                              hipStream_t stream) {
    const float* x = (const float*)d_in[0];   // [B,4] fp32
    const float* w = (const float*)d_in[1];   // [3,4,3] fp32
    float* out = (float*)d_out;               // [B,4] fp32
    int B = in_sizes[0] / 4;

    int grid = (B + BLOCK * SPT - 1) / (BLOCK * SPT);
    qnat_fused<<<grid, BLOCK, 0, stream>>>((const float4*)x, w, (float4*)out, B);
}